// Round 4
// baseline (9911.142 us; speedup 1.0000x reference)
//
#include <hip/hip_runtime.h>
#include <hip/hip_bf16.h>
#include <stdint.h>

typedef __attribute__((ext_vector_type(8))) short bf16x8;
typedef __attribute__((ext_vector_type(4))) float f32x4;

__device__ __forceinline__ unsigned short f2bf(float f) {
    union { float f; unsigned u; } v; v.f = f;
    unsigned r = v.u + 0x7fffu + ((v.u >> 16) & 1u);
    return (unsigned short)(r >> 16);
}
__device__ __forceinline__ float bf2f(unsigned short h) {
    union { unsigned u; float f; } v; v.u = ((unsigned)h) << 16;
    return v.f;
}

// ---------------------------------------------------------------------------
// Gather-GEMM, all-register: out[N,256] = sum_k in[neigh[:,k]] @ Wt[k]^T
// Wt: [NK, 256, CIN] bf16. Block: 512 thr = 8 waves (2x4), wave tile 64x64,
// BM=128 rows, BN=256 (full width => each gathered row fetched once per k).
// A and B fragments are loaded DIRECTLY to VGPRs (no LDS staging, no
// barriers): per-wave independent 2-deep software pipeline hides gather
// latency; fragment layout (16B/lane, 4 lanes/row contiguous) gives fully
// used 64B lines. Only LDS use: neighbor indices (13.5 KB).
// ---------------------------------------------------------------------------
template<int CIN, bool GATHER, bool OUT_BF16>
__global__ __launch_bounds__(512, 2) void conv_kernel(
    const unsigned short* __restrict__ in,     // [Npad, CIN] bf16
    const int* __restrict__ neigh,             // [N, 27]
    const unsigned short* __restrict__ Wt,     // [NK, 256, CIN] bf16
    void* __restrict__ outp,                   // bf16 or f32 [N,256]
    float* __restrict__ stats,                 // [2][256]
    int N, int NK)
{
    constexpr int NKT = CIN / 64;              // K-tiles of 64 per k-offset
    __shared__ int nlds[GATHER ? 128 * 27 : 8];

    const int tid  = threadIdx.x;
    const int lane = tid & 63;
    const int wid  = tid >> 6;
    const int wr   = wid >> 2, wc = wid & 3;   // 2x4 wave grid, each 64x64
    const int brow = blockIdx.x * 128;

    if (GATHER) {
        for (int s = tid; s < 128 * 27; s += 512) {
            int r = s / 27, kk = s - r * 27;
            int grow = brow + r;
            nlds[s] = (grow < N) ? neigh[(size_t)grow * 27 + kk] : 0;
        }
        __syncthreads();
    }

    const int rbase = wr * 64 + (lane & 15);   // + m*16 -> this lane's A rows
    const int chunk = (lane >> 4) * 16;        // byte offset of 16B k-chunk

    // per-lane B row byte offsets (constant over k, kt)
    int boff[4];
    #pragma unroll
    for (int n = 0; n < 4; ++n)
        boff[n] = (wc * 64 + n * 16 + (lane & 15)) * CIN * 2 + chunk;

    struct Frag { bf16x8 a[4][2]; bf16x8 b[4][2]; };   // 64 VGPR

    f32x4 acc[4][4] = {};
    Frag F0, F1;
    int idc[4], idn[4];

    auto loadidx = [&](int k, int* id) {
        #pragma unroll
        for (int m = 0; m < 4; ++m)
            id[m] = GATHER ? nlds[(rbase + m * 16) * 27 + k] : (brow + rbase + m * 16);
    };
    auto loadfrag = [&](Frag& F, const int* id, int k, int kt) {
        const char* wb = (const char*)Wt + ((size_t)k * 256 * CIN) * 2 + kt * 128;
        #pragma unroll
        for (int n = 0; n < 4; ++n) {
            F.b[n][0] = *(const bf16x8*)(wb + boff[n]);
            F.b[n][1] = *(const bf16x8*)(wb + boff[n] + 64);
        }
        #pragma unroll
        for (int m = 0; m < 4; ++m) {
            const char* ab = (const char*)in + ((size_t)id[m] * CIN) * 2 + kt * 128 + chunk;
            F.a[m][0] = *(const bf16x8*)(ab);
            F.a[m][1] = *(const bf16x8*)(ab + 64);
        }
    };
    auto domfma = [&](Frag& F) {
        #pragma unroll
        for (int m = 0; m < 4; ++m)
            #pragma unroll
            for (int n = 0; n < 4; ++n) {
                acc[m][n] = __builtin_amdgcn_mfma_f32_16x16x32_bf16(F.a[m][0], F.b[n][0], acc[m][n], 0, 0, 0);
                acc[m][n] = __builtin_amdgcn_mfma_f32_16x16x32_bf16(F.a[m][1], F.b[n][1], acc[m][n], 0, 0, 0);
            }
    };

    loadidx(0, idc);
    loadfrag(F0, idc, 0, 0);

    for (int k = 0; k < NK; ++k) {
        if (GATHER && k + 1 < NK) loadidx(k + 1, idn);
        #pragma unroll
        for (int kt = 0; kt < NKT; ++kt) {
            // cur/nxt alternate statically (NKT is 2 or 4 -> even, so the
            // frag loaded for (k+1,0) lands in F0, matching next k's kt=0).
            if ((kt & 1) == 0) {
                if (kt + 1 < NKT)      loadfrag(F1, idc, k, kt + 1);
                else if (k + 1 < NK)   loadfrag(F1, idn, k + 1, 0);
                domfma(F0);
            } else {
                if (kt + 1 < NKT)      loadfrag(F0, idc, k, kt + 1);
                else if (k + 1 < NK)   loadfrag(F0, idn, k + 1, 0);
                domfma(F1);
            }
        }
        if (GATHER) {
            #pragma unroll
            for (int m = 0; m < 4; ++m) idc[m] = idn[m];
        } else {
            // !GATHER has NK==1; loop ends.
        }
    }

    // --- per-column stats (masked for pad rows)
    #pragma unroll
    for (int n = 0; n < 4; ++n) {
        float s = 0.f, q = 0.f;
        #pragma unroll
        for (int m = 0; m < 4; ++m)
            #pragma unroll
            for (int j = 0; j < 4; ++j) {
                int row = brow + wr * 64 + m * 16 + ((lane >> 4) * 4) + j;
                float v = (row < N) ? acc[m][n][j] : 0.f;
                s += v; q += v * v;
            }
        s += __shfl_xor(s, 16); s += __shfl_xor(s, 32);
        q += __shfl_xor(q, 16); q += __shfl_xor(q, 32);
        if (lane < 16) {
            int col = wc * 64 + n * 16 + lane;
            atomicAdd(&stats[col], s);
            atomicAdd(&stats[256 + col], q);
        }
    }
    // --- store raw output (C/D map: col=lane&15, row=(lane>>4)*4+j)
    #pragma unroll
    for (int m = 0; m < 4; ++m) {
        #pragma unroll
        for (int j = 0; j < 4; ++j) {
            int row = brow + wr * 64 + m * 16 + ((lane >> 4) * 4) + j;
            if (row < N) {
                #pragma unroll
                for (int n = 0; n < 4; ++n) {
                    int col = wc * 64 + n * 16 + (lane & 15);
                    float v = acc[m][n][j];
                    if (OUT_BF16)
                        ((unsigned short*)outp)[(size_t)row * 256 + col] = f2bf(v);
                    else
                        __builtin_nontemporal_store(v, &((float*)outp)[(size_t)row * 256 + col]);
                }
            }
        }
    }
}

// ---------------------------------------------------------------------------
// small helper kernels
// ---------------------------------------------------------------------------
__global__ void cast_x_kernel(const float* __restrict__ x, unsigned short* __restrict__ xb, size_t n8) {
    size_t stride = (size_t)gridDim.x * blockDim.x;
    for (size_t i = (size_t)blockIdx.x * blockDim.x + threadIdx.x; i < n8; i += stride) {
        const float4* p = (const float4*)(x + i * 8);
        float4 f0 = p[0], f1 = p[1];
        unsigned short o[8];
        o[0] = f2bf(f0.x); o[1] = f2bf(f0.y); o[2] = f2bf(f0.z); o[3] = f2bf(f0.w);
        o[4] = f2bf(f1.x); o[5] = f2bf(f1.y); o[6] = f2bf(f1.z); o[7] = f2bf(f1.w);
        *(uint4*)(xb + i * 8) = *(uint4*)o;
    }
}

// w: [NK,CI,CO] f32  ->  wt: [NK,CO,CI] bf16
__global__ void cast_wT_kernel(const float* __restrict__ w, unsigned short* __restrict__ wt,
                               int NK, int CI, int CO) {
    int total = NK * CI * CO;
    int stride = gridDim.x * blockDim.x;
    for (int id = blockIdx.x * blockDim.x + threadIdx.x; id < total; id += stride) {
        int ci = id % CI;
        int t  = id / CI;
        int co = t % CO;
        int k  = t / CO;
        wt[id] = f2bf(w[((size_t)k * CI + ci) * CO + co]);
    }
}

__global__ void finalize_kernel(const float* __restrict__ stats, const float* __restrict__ gamma,
                                const float* __restrict__ beta, float* __restrict__ coef, float invN) {
    int c = threadIdx.x;
    float mean = stats[c] * invN;
    float var  = fmaxf(stats[256 + c] * invN - mean * mean, 0.f);
    float a = gamma[c] * rsqrtf(var + 1e-5f);
    coef[c] = a;
    coef[256 + c] = beta[c] - mean * a;
}

// in-place bf16: x = relu(x*a[c] + b[c])
__global__ void bn_relu_kernel(unsigned short* __restrict__ buf, const float* __restrict__ coef, size_t n8) {
    size_t stride = (size_t)gridDim.x * blockDim.x;
    for (size_t i = (size_t)blockIdx.x * blockDim.x + threadIdx.x; i < n8; i += stride) {
        uint4 v = *(uint4*)(buf + i * 8);
        unsigned short* h = (unsigned short*)&v;
        int cb = (int)((i * 8) & 255);
        #pragma unroll
        for (int j = 0; j < 8; ++j) {
            float f = bf2f(h[j]) * coef[cb + j] + coef[256 + cb + j];
            h[j] = f2bf(fmaxf(f, 0.f));
        }
        *(uint4*)(buf + i * 8) = v;
    }
}

// out = relu(out*a2+b2 + sc*as+bs), out f32 in-place, sc bf16
__global__ void final_kernel(float* __restrict__ out, const unsigned short* __restrict__ sc,
                             const float* __restrict__ c2, const float* __restrict__ cs, size_t n4) {
    size_t stride = (size_t)gridDim.x * blockDim.x;
    for (size_t i = (size_t)blockIdx.x * blockDim.x + threadIdx.x; i < n4; i += stride) {
        float4 o = *(float4*)(out + i * 4);
        ushort4 s4 = *(const ushort4*)(sc + i * 4);
        int cb = (int)((i * 4) & 255);
        float r;
        r = o.x * c2[cb + 0] + c2[256 + cb + 0] + bf2f(s4.x) * cs[cb + 0] + cs[256 + cb + 0]; o.x = fmaxf(r, 0.f);
        r = o.y * c2[cb + 1] + c2[256 + cb + 1] + bf2f(s4.y) * cs[cb + 1] + cs[256 + cb + 1]; o.y = fmaxf(r, 0.f);
        r = o.z * c2[cb + 2] + c2[256 + cb + 2] + bf2f(s4.z) * cs[cb + 2] + cs[256 + cb + 2]; o.z = fmaxf(r, 0.f);
        r = o.w * c2[cb + 3] + c2[256 + cb + 3] + bf2f(s4.w) * cs[cb + 3] + cs[256 + cb + 3]; o.w = fmaxf(r, 0.f);
        *(float4*)(out + i * 4) = o;
    }
}

// ---------------------------------------------------------------------------
extern "C" void kernel_launch(void* const* d_in, const int* in_sizes, int n_in,
                              void* d_out, int out_size, void* d_ws, size_t ws_size,
                              hipStream_t stream) {
    const float* data = (const float*)d_in[0];
    const int*   neigh = (const int*)d_in[1];
    // d_in[2] = depth (unused)
    const float* Wa = (const float*)d_in[3];
    const float* ga = (const float*)d_in[4];
    const float* ba = (const float*)d_in[5];
    const float* Wb = (const float*)d_in[6];
    const float* gb = (const float*)d_in[7];
    const float* bb = (const float*)d_in[8];
    const float* W1 = (const float*)d_in[9];
    const float* gs = (const float*)d_in[10];
    const float* bs = (const float*)d_in[11];

    const int N = in_sizes[0] / 128;
    const int nblk = (N + 127) / 128;
    const int Npad = nblk * 128;

    // ws layout
    char* ws = (char*)d_ws;
    float* stats1 = (float*)(ws + 0);        // [2][256]
    float* stats2 = (float*)(ws + 2048);
    float* statss = (float*)(ws + 4096);
    float* c1     = (float*)(ws + 6144);     // [2][256] scale/shift
    float* c2     = (float*)(ws + 8192);
    float* cs     = (float*)(ws + 10240);
    unsigned short* WaT = (unsigned short*)(ws + 16384);      // [27][256][128]
    unsigned short* WbT = WaT + (size_t)27 * 256 * 128;       // [27][256][256]
    unsigned short* W1T = WbT + (size_t)27 * 256 * 256;       // [256][128]
    unsigned short* Xb  = W1T + (size_t)256 * 128;            // [Npad][128] bf16
    unsigned short* buf1 = Xb + (size_t)Npad * 128;           // [Npad][256] bf16

    hipMemsetAsync(d_ws, 0, 16384, stream);   // stats + coefs
    if (Npad > N)                              // zero Xb pad rows
        hipMemsetAsync(Xb + (size_t)N * 128, 0, (size_t)(Npad - N) * 128 * 2, stream);

    cast_x_kernel<<<2048, 256, 0, stream>>>(data, Xb, (size_t)N * 128 / 8);
    cast_wT_kernel<<<1024, 256, 0, stream>>>(Wa, WaT, 27, 128, 256);
    cast_wT_kernel<<<1024, 256, 0, stream>>>(Wb, WbT, 27, 256, 256);
    cast_wT_kernel<<<64, 256, 0, stream>>>(W1, W1T, 1, 128, 256);

    // conv1: gather Xb -> raw bf16 + stats1
    conv_kernel<128, true, true><<<nblk, 512, 0, stream>>>(Xb, neigh, WaT, buf1, stats1, N, 27);
    finalize_kernel<<<1, 256, 0, stream>>>(stats1, ga, ba, c1, 1.0f / N);
    bn_relu_kernel<<<2048, 256, 0, stream>>>(buf1, c1, (size_t)N * 256 / 8);
    // conv2: gather normalized conv1 -> raw f32 into d_out + stats2
    conv_kernel<256, true, false><<<nblk, 512, 0, stream>>>(buf1, neigh, WbT, d_out, stats2, N, 27);
    // shortcut: dense Xb @ W1 -> raw bf16 (buf1 already consumed by conv2)
    conv_kernel<128, false, true><<<nblk, 512, 0, stream>>>(Xb, nullptr, W1T, buf1, statss, N, 1);
    finalize_kernel<<<1, 256, 0, stream>>>(stats2, gb, bb, c2, 1.0f / N);
    finalize_kernel<<<1, 256, 0, stream>>>(statss, gs, bs, cs, 1.0f / N);
    // out = relu(bn(conv2) + bn(shortcut))
    final_kernel<<<2048, 256, 0, stream>>>((float*)d_out, buf1, c2, cs, (size_t)N * 256 / 4);
}

// Round 5
// 4746.641 us; speedup vs baseline: 2.0880x; 2.0880x over previous
//
#include <hip/hip_runtime.h>
#include <hip/hip_bf16.h>
#include <stdint.h>

typedef __attribute__((ext_vector_type(8))) short bf16x8;
typedef __attribute__((ext_vector_type(4))) float f32x4;

#define AS1(p) ((const __attribute__((address_space(1))) void*)(p))
#define AS3(p) ((__attribute__((address_space(3))) void*)(p))

__device__ __forceinline__ unsigned short f2bf(float f) {
    union { float f; unsigned u; } v; v.f = f;
    unsigned r = v.u + 0x7fffu + ((v.u >> 16) & 1u);
    return (unsigned short)(r >> 16);
}
__device__ __forceinline__ float bf2f(unsigned short h) {
    union { unsigned u; float f; } v; v.u = ((unsigned)h) << 16;
    return v.f;
}

// ---------------------------------------------------------------------------
// Gather-GEMM: out[N,256] = sum_k in[neigh[:,k]] @ Wt[k]^T   (Wt: [NK,256,CIN])
// BM=128 x BN=256, 512 threads (8 waves 2x4, each 64x64), KT=64.
// Deep prefetch to keep the random-gather stream saturated:
//   A: 3 LDS buffers, issued 2 tiles ahead (2 gload_lds/thread/tile)
//   B: 2 LDS buffers, issued 1 tile ahead (4 gload_lds/thread/tile)
// Issue order per iter t: [B(t+1), A(t+2)] so the in-order vmcnt keeps
// {A(t+1), B(t+1), A(t+2)} = 8 insts/wave in flight across the wait+barrier.
// ---------------------------------------------------------------------------
template<int CIN, bool GATHER, bool OUT_BF16>
__global__ __launch_bounds__(512, 2) void conv_kernel(
    const unsigned short* __restrict__ in,     // [Npad, CIN] bf16
    const int* __restrict__ neigh,             // [N, 27]
    const unsigned short* __restrict__ Wt,     // [NK, 256, CIN] bf16
    void* __restrict__ outp,                   // bf16 or f32 [N,256]
    float* __restrict__ stats,                 // [2][256]
    int N, int NK)
{
    constexpr int KT = 64;
    constexpr int NKT = CIN / KT;
    __shared__ unsigned short Alds[3][128 * KT];   // 3 x 16 KB
    __shared__ unsigned short Blds[2][256 * KT];   // 2 x 32 KB
    __shared__ int nlds[GATHER ? 128 * 27 : 8];    // 13.5 KB

    const int tid  = threadIdx.x;
    const int lane = tid & 63;
    const int wid  = tid >> 6;
    const int wr   = wid >> 2, wc = wid & 3;       // 2x4 wave grid, each 64x64
    const int brow = blockIdx.x * 128;

    if (GATHER) {
        for (int s = tid; s < 128 * 27; s += 512) {
            int r = s / 27, kk = s - r * 27;
            int grow = brow + r;
            nlds[s] = (grow < N) ? neigh[(size_t)grow * 27 + kk] : 0;
        }
        __syncthreads();
    }

    const int T = NK * NKT;

    auto stageA = [&](int t) {
        const int k = t / NKT, kt = t - (t / NKT) * NKT;
        char* dst = (char*)&Alds[t % 3][0];
        #pragma unroll
        for (int i = 0; i < 2; ++i) {               // 128 rows x 128B
            int s = i * 512 + tid;
            int r = s >> 3, seg = s & 7;
            int g = GATHER ? nlds[r * 27 + k] : (brow + r);
            const char* src = (const char*)in + ((size_t)g * CIN + kt * KT) * 2
                            + ((seg ^ (r & 7)) * 16);
            __builtin_amdgcn_global_load_lds(AS1(src),
                AS3(dst + (i * 512 + wid * 64) * 16), 16, 0, 0);
        }
    };
    auto stageB = [&](int t) {
        const int k = t / NKT, kt = t - (t / NKT) * NKT;
        char* dst = (char*)&Blds[t & 1][0];
        #pragma unroll
        for (int i = 0; i < 4; ++i) {               // 256 cols x 128B
            int s = i * 512 + tid;
            int c = s >> 3, seg = s & 7;
            const char* src = (const char*)Wt
                + (((size_t)k * 256 + c) * CIN + kt * KT) * 2
                + ((seg ^ (c & 7)) * 16);
            __builtin_amdgcn_global_load_lds(AS1(src),
                AS3(dst + (i * 512 + wid * 64) * 16), 16, 0, 0);
        }
    };

    f32x4 acc[4][4] = {};

    // prologue: order matters for the in-order vmcnt math: A(0), B(0), A(1)
    stageA(0);
    stageB(0);
    if (T > 1) stageA(1);

    for (int t = 0; t < T; ++t) {
        // issue next stages FIRST so they ride through the wait+barrier
        if (t + 1 < T) stageB(t + 1);
        if (t + 2 < T) stageA(t + 2);
        __builtin_amdgcn_sched_barrier(0);
        // wait for A(t), B(t); leave newer {A(t+1), B(t+1), A(t+2)} in flight
        if (t + 2 < T)      asm volatile("s_waitcnt vmcnt(8)" ::: "memory");
        else if (t + 1 < T) asm volatile("s_waitcnt vmcnt(6)" ::: "memory");
        else                asm volatile("s_waitcnt vmcnt(0)" ::: "memory");
        __builtin_amdgcn_sched_barrier(0);
        __builtin_amdgcn_s_barrier();
        __builtin_amdgcn_sched_barrier(0);

        const char* Ab = (const char*)&Alds[t % 3][0];
        const char* Bb = (const char*)&Blds[t & 1][0];
        bf16x8 bfr[4][2];
        #pragma unroll
        for (int n = 0; n < 4; ++n)
            #pragma unroll
            for (int kk = 0; kk < 2; ++kk) {
                int c = wc * 64 + n * 16 + (lane & 15);
                int byte = (c * 128 + kk * 64 + ((lane >> 4) * 16)) ^ ((c & 7) << 4);
                bfr[n][kk] = *(const bf16x8*)(Bb + byte);
            }
        #pragma unroll
        for (int m = 0; m < 4; ++m) {
            bf16x8 af[2];
            #pragma unroll
            for (int kk = 0; kk < 2; ++kk) {
                int r = wr * 64 + m * 16 + (lane & 15);
                int byte = (r * 128 + kk * 64 + ((lane >> 4) * 16)) ^ ((r & 7) << 4);
                af[kk] = *(const bf16x8*)(Ab + byte);
            }
            __builtin_amdgcn_s_setprio(1);
            #pragma unroll
            for (int n = 0; n < 4; ++n) {
                acc[m][n] = __builtin_amdgcn_mfma_f32_16x16x32_bf16(af[0], bfr[n][0], acc[m][n], 0, 0, 0);
                acc[m][n] = __builtin_amdgcn_mfma_f32_16x16x32_bf16(af[1], bfr[n][1], acc[m][n], 0, 0, 0);
            }
            __builtin_amdgcn_s_setprio(0);
        }
        __builtin_amdgcn_sched_barrier(0);
        __builtin_amdgcn_s_barrier();               // all reads of tile t's buffers done
        __builtin_amdgcn_sched_barrier(0);
    }

    // --- per-column stats (masked for pad rows)
    #pragma unroll
    for (int n = 0; n < 4; ++n) {
        float s = 0.f, q = 0.f;
        #pragma unroll
        for (int m = 0; m < 4; ++m)
            #pragma unroll
            for (int j = 0; j < 4; ++j) {
                int row = brow + wr * 64 + m * 16 + ((lane >> 4) * 4) + j;
                float v = (row < N) ? acc[m][n][j] : 0.f;
                s += v; q += v * v;
            }
        s += __shfl_xor(s, 16); s += __shfl_xor(s, 32);
        q += __shfl_xor(q, 16); q += __shfl_xor(q, 32);
        if (lane < 16) {
            int col = wc * 64 + n * 16 + lane;
            atomicAdd(&stats[col], s);
            atomicAdd(&stats[256 + col], q);
        }
    }
    // --- store raw output (C/D map: col=lane&15, row=(lane>>4)*4+j)
    #pragma unroll
    for (int m = 0; m < 4; ++m) {
        #pragma unroll
        for (int j = 0; j < 4; ++j) {
            int row = brow + wr * 64 + m * 16 + ((lane >> 4) * 4) + j;
            if (row < N) {
                #pragma unroll
                for (int n = 0; n < 4; ++n) {
                    int col = wc * 64 + n * 16 + (lane & 15);
                    float v = acc[m][n][j];
                    if (OUT_BF16)
                        ((unsigned short*)outp)[(size_t)row * 256 + col] = f2bf(v);
                    else
                        __builtin_nontemporal_store(v, &((float*)outp)[(size_t)row * 256 + col]);
                }
            }
        }
    }
}

// ---------------------------------------------------------------------------
// small helper kernels
// ---------------------------------------------------------------------------
__global__ void cast_x_kernel(const float* __restrict__ x, unsigned short* __restrict__ xb, size_t n8) {
    size_t stride = (size_t)gridDim.x * blockDim.x;
    for (size_t i = (size_t)blockIdx.x * blockDim.x + threadIdx.x; i < n8; i += stride) {
        const float4* p = (const float4*)(x + i * 8);
        float4 f0 = p[0], f1 = p[1];
        unsigned short o[8];
        o[0] = f2bf(f0.x); o[1] = f2bf(f0.y); o[2] = f2bf(f0.z); o[3] = f2bf(f0.w);
        o[4] = f2bf(f1.x); o[5] = f2bf(f1.y); o[6] = f2bf(f1.z); o[7] = f2bf(f1.w);
        *(uint4*)(xb + i * 8) = *(uint4*)o;
    }
}

// w: [NK,CI,CO] f32  ->  wt: [NK,CO,CI] bf16
__global__ void cast_wT_kernel(const float* __restrict__ w, unsigned short* __restrict__ wt,
                               int NK, int CI, int CO) {
    int total = NK * CI * CO;
    int stride = gridDim.x * blockDim.x;
    for (int id = blockIdx.x * blockDim.x + threadIdx.x; id < total; id += stride) {
        int ci = id % CI;
        int t  = id / CI;
        int co = t % CO;
        int k  = t / CO;
        wt[id] = f2bf(w[((size_t)k * CI + ci) * CO + co]);
    }
}

__global__ void finalize_kernel(const float* __restrict__ stats, const float* __restrict__ gamma,
                                const float* __restrict__ beta, float* __restrict__ coef, float invN) {
    int c = threadIdx.x;
    float mean = stats[c] * invN;
    float var  = fmaxf(stats[256 + c] * invN - mean * mean, 0.f);
    float a = gamma[c] * rsqrtf(var + 1e-5f);
    coef[c] = a;
    coef[256 + c] = beta[c] - mean * a;
}

// in-place bf16: x = relu(x*a[c] + b[c])
__global__ void bn_relu_kernel(unsigned short* __restrict__ buf, const float* __restrict__ coef, size_t n8) {
    size_t stride = (size_t)gridDim.x * blockDim.x;
    for (size_t i = (size_t)blockIdx.x * blockDim.x + threadIdx.x; i < n8; i += stride) {
        uint4 v = *(uint4*)(buf + i * 8);
        unsigned short* h = (unsigned short*)&v;
        int cb = (int)((i * 8) & 255);
        #pragma unroll
        for (int j = 0; j < 8; ++j) {
            float f = bf2f(h[j]) * coef[cb + j] + coef[256 + cb + j];
            h[j] = f2bf(fmaxf(f, 0.f));
        }
        *(uint4*)(buf + i * 8) = v;
    }
}

// out = relu(out*a2+b2 + sc*as+bs), out f32 in-place, sc bf16
__global__ void final_kernel(float* __restrict__ out, const unsigned short* __restrict__ sc,
                             const float* __restrict__ c2, const float* __restrict__ cs, size_t n4) {
    size_t stride = (size_t)gridDim.x * blockDim.x;
    for (size_t i = (size_t)blockIdx.x * blockDim.x + threadIdx.x; i < n4; i += stride) {
        float4 o = *(float4*)(out + i * 4);
        ushort4 s4 = *(const ushort4*)(sc + i * 4);
        int cb = (int)((i * 4) & 255);
        float r;
        r = o.x * c2[cb + 0] + c2[256 + cb + 0] + bf2f(s4.x) * cs[cb + 0] + cs[256 + cb + 0]; o.x = fmaxf(r, 0.f);
        r = o.y * c2[cb + 1] + c2[256 + cb + 1] + bf2f(s4.y) * cs[cb + 1] + cs[256 + cb + 1]; o.y = fmaxf(r, 0.f);
        r = o.z * c2[cb + 2] + c2[256 + cb + 2] + bf2f(s4.z) * cs[cb + 2] + cs[256 + cb + 2]; o.z = fmaxf(r, 0.f);
        r = o.w * c2[cb + 3] + c2[256 + cb + 3] + bf2f(s4.w) * cs[cb + 3] + cs[256 + cb + 3]; o.w = fmaxf(r, 0.f);
        *(float4*)(out + i * 4) = o;
    }
}

// ---------------------------------------------------------------------------
extern "C" void kernel_launch(void* const* d_in, const int* in_sizes, int n_in,
                              void* d_out, int out_size, void* d_ws, size_t ws_size,
                              hipStream_t stream) {
    const float* data = (const float*)d_in[0];
    const int*   neigh = (const int*)d_in[1];
    // d_in[2] = depth (unused)
    const float* Wa = (const float*)d_in[3];
    const float* ga = (const float*)d_in[4];
    const float* ba = (const float*)d_in[5];
    const float* Wb = (const float*)d_in[6];
    const float* gb = (const float*)d_in[7];
    const float* bb = (const float*)d_in[8];
    const float* W1 = (const float*)d_in[9];
    const float* gs = (const float*)d_in[10];
    const float* bs = (const float*)d_in[11];

    const int N = in_sizes[0] / 128;
    const int nblk = (N + 127) / 128;
    const int Npad = nblk * 128;

    // ws layout
    char* ws = (char*)d_ws;
    float* stats1 = (float*)(ws + 0);        // [2][256]
    float* stats2 = (float*)(ws + 2048);
    float* statss = (float*)(ws + 4096);
    float* c1     = (float*)(ws + 6144);     // [2][256] scale/shift
    float* c2     = (float*)(ws + 8192);
    float* cs     = (float*)(ws + 10240);
    unsigned short* WaT = (unsigned short*)(ws + 16384);      // [27][256][128]
    unsigned short* WbT = WaT + (size_t)27 * 256 * 128;       // [27][256][256]
    unsigned short* W1T = WbT + (size_t)27 * 256 * 256;       // [256][128]
    unsigned short* Xb  = W1T + (size_t)256 * 128;            // [Npad][128] bf16
    unsigned short* buf1 = Xb + (size_t)Npad * 128;           // [Npad][256] bf16

    hipMemsetAsync(d_ws, 0, 16384, stream);   // stats + coefs
    if (Npad > N)                              // zero Xb pad rows
        hipMemsetAsync(Xb + (size_t)N * 128, 0, (size_t)(Npad - N) * 128 * 2, stream);

    cast_x_kernel<<<2048, 256, 0, stream>>>(data, Xb, (size_t)N * 128 / 8);
    cast_wT_kernel<<<1024, 256, 0, stream>>>(Wa, WaT, 27, 128, 256);
    cast_wT_kernel<<<1024, 256, 0, stream>>>(Wb, WbT, 27, 256, 256);
    cast_wT_kernel<<<64, 256, 0, stream>>>(W1, W1T, 1, 128, 256);

    // conv1: gather Xb -> raw bf16 + stats1
    conv_kernel<128, true, true><<<nblk, 512, 0, stream>>>(Xb, neigh, WaT, buf1, stats1, N, 27);
    finalize_kernel<<<1, 256, 0, stream>>>(stats1, ga, ba, c1, 1.0f / N);
    bn_relu_kernel<<<2048, 256, 0, stream>>>(buf1, c1, (size_t)N * 256 / 8);
    // conv2: gather normalized conv1 -> raw f32 into d_out + stats2
    conv_kernel<256, true, false><<<nblk, 512, 0, stream>>>(buf1, neigh, WbT, d_out, stats2, N, 27);
    // shortcut: dense Xb @ W1 -> raw bf16 (buf1 already consumed by conv2)
    conv_kernel<128, false, true><<<nblk, 512, 0, stream>>>(Xb, nullptr, W1T, buf1, statss, N, 1);
    finalize_kernel<<<1, 256, 0, stream>>>(stats2, gb, bb, c2, 1.0f / N);
    finalize_kernel<<<1, 256, 0, stream>>>(statss, gs, bs, cs, 1.0f / N);
    // out = relu(bn(conv2) + bn(shortcut))
    final_kernel<<<2048, 256, 0, stream>>>((float*)d_out, buf1, c2, cs, (size_t)N * 256 / 4);
}